// Round 2
// baseline (172.050 us; speedup 1.0000x reference)
//
#include <hip/hip_runtime.h>

typedef unsigned short u16;
typedef __attribute__((ext_vector_type(8))) short s16x8;
typedef __attribute__((ext_vector_type(4))) float f32x4;

// f32 -> bf16 bits, round-to-nearest-even (values are finite)
__device__ __forceinline__ u16 f2bf(float f) {
    unsigned u = __builtin_bit_cast(unsigned, f);
    u += 0x7fffu + ((u >> 16) & 1u);
    return (u16)(u >> 16);
}

// ws layout (floats): [0..127] Sx[n][c], [128..255] Sx2[n][c],
// [256..8447] A[n][o][c] (2*4096), [8448..8575] K[n][o]
#define WS_SX   0
#define WS_SX2  128
#define WS_A    256
#define WS_K    8448

// ---------------- Kernel 1: per-(n,c) moments of x (fp32) ----------------
__global__ __launch_bounds__(256) void k_reduce(const float* __restrict__ x,
                                                float* __restrict__ ws) {
    int nc = blockIdx.x;                       // 0..127, one 4096-elem channel each
    const f32x4* p = (const f32x4*)(x + (size_t)nc * 4096);
    int t = threadIdx.x;
    float s = 0.f, s2 = 0.f;
    for (int it = 0; it < 4; ++it) {
        f32x4 v = p[t + it * 256];
        for (int e = 0; e < 4; ++e) { s += v[e]; s2 += v[e] * v[e]; }
    }
    for (int off = 32; off; off >>= 1) {
        s  += __shfl_down(s, off);
        s2 += __shfl_down(s2, off);
    }
    __shared__ float rs[4], rs2[4];
    int lane = t & 63, wv = t >> 6;
    if (lane == 0) { rs[wv] = s; rs2[wv] = s2; }
    __syncthreads();
    if (t == 0) {
        ws[WS_SX  + nc] = rs[0] + rs[1] + rs[2] + rs[3];
        ws[WS_SX2 + nc] = rs2[0] + rs2[1] + rs2[2] + rs2[3];
    }
}

// ---------------- Kernel 2: analytic GN stats + fold into A, K ----------------
__global__ __launch_bounds__(256) void k_stats(const float* __restrict__ w_ct,
                                               const float* __restrict__ b_ct,
                                               const float* __restrict__ gamma,
                                               const float* __restrict__ beta,
                                               const float* __restrict__ w_pw,
                                               float* __restrict__ ws) {
    __shared__ float s_sw[64], s_sw2[64], s_b[64], s_g[64], s_be[64];
    __shared__ float s_wpw[4096];
    __shared__ float s_mean[2], s_inv[2];
    int t = threadIdx.x;
    if (t < 64) {
        int c = t;
        float sw = 0.f, sw2 = 0.f;
        for (int q = 0; q < 64; ++q) {
            float w = w_ct[c * 64 + q];
            sw += w; sw2 += w * w;
        }
        s_sw[c] = sw; s_sw2[c] = sw2;
        s_b[c] = b_ct[c]; s_g[c] = gamma[c]; s_be[c] = beta[c];
    }
    for (int idx = t; idx < 4096; idx += 256) s_wpw[idx] = w_pw[idx];
    __syncthreads();
    if (t < 64) {
        int c = t;
        for (int n = 0; n < 2; ++n) {
            float sx  = ws[WS_SX  + n * 64 + c];
            float sx2 = ws[WS_SX2 + n * 64 + c];
            // y = x*w + b over 4096 coarse voxels * 64 taps = 262144 elems/channel
            float ty  = s_sw[c]  * sx  + 262144.f * s_b[c];
            float ty2 = s_sw2[c] * sx2 + 2.f * s_b[c] * s_sw[c] * sx
                        + 262144.f * s_b[c] * s_b[c];
            for (int off = 32; off; off >>= 1) {
                ty  += __shfl_down(ty, off);
                ty2 += __shfl_down(ty2, off);
            }
            if (t == 0) {
                float mean = ty * (1.f / 16777216.f);
                float var  = ty2 * (1.f / 16777216.f) - mean * mean;
                s_mean[n] = mean;
                s_inv[n]  = rsqrtf(var + 1e-5f);
            }
        }
    }
    __syncthreads();
    // A[n][o][c] = w_pw[o,c] * gamma[c] * inv_std_n
    for (int n = 0; n < 2; ++n) {
        float inv = s_inv[n];
        for (int idx = t; idx < 4096; idx += 256) {
            int c = idx & 63;
            ws[WS_A + n * 4096 + idx] = s_wpw[idx] * s_g[c] * inv;
        }
    }
    // K[n][o] = sum_c w_pw[o,c] * (b_ct[c]*scale_c + beta[c] - mean*scale_c)
    if (t < 128) {
        int n = t >> 6, o = t & 63;
        float inv = s_inv[n], mean = s_mean[n], k = 0.f;
        for (int c = 0; c < 64; ++c) {
            float scale = s_g[c] * inv;
            float shift = s_be[c] - mean * scale;
            k += s_wpw[o * 64 + c] * (s_b[c] * scale + shift);
        }
        ws[WS_K + t] = k;
    }
}

// ---------------- Kernel 3: fused upsample+GN+pointwise via MFMA ----------------
// Block = (n, d, h). Computes out[n, :, 4d+i, 4h+j, :] for all o,i,j,W.
// GEMM (transposed): D[q][o] = B[c][q]^T @ A[o][c]^T + K[o]
//   q = (i*4+j)*64 + W, W = 4w+k,  B[c][q] = w_ct[c,i,j,k] * x[n,c,d,h,w]
// Using mfma(bfrag, afrag, acc): rows = q (so each lane's 4 acc regs are 4
// consecutive W of one channel -> float4 store), cols = o.
__global__ __launch_bounds__(256) void k_main(const float* __restrict__ x,
                                              const float* __restrict__ w_ct,
                                              const float* __restrict__ ws,
                                              float* __restrict__ out) {
    __shared__ __align__(16) float sW[64 * 64];   // [ijk][c], c contiguous
    __shared__ __align__(16) float sX[16 * 64];   // [w][c],   c contiguous
    __shared__ __align__(16) float sA[64 * 68];   // [o][c], stride 68 (bank spread)
    __shared__ float sK[64];

    int t = threadIdx.x;
    int b = blockIdx.x;
    int n = b >> 8, d = (b >> 4) & 15, h = b & 15;

    // ---- stage A (fp32, coalesced) ----
    const float* Aws = ws + WS_A + n * 4096;
    for (int idx = t; idx < 4096; idx += 256)
        sA[(idx >> 6) * 68 + (idx & 63)] = Aws[idx];
    if (t < 64) sK[t] = ws[WS_K + n * 64 + t];

    // ---- stage transposed w_ct and x row (threads 0..63 = c) ----
    if (t < 64) {
        int c = t;
        const f32x4* wp = (const f32x4*)(w_ct + c * 64);
        for (int r = 0; r < 16; ++r) {
            f32x4 v = wp[r];
            for (int e = 0; e < 4; ++e) sW[(r * 4 + e) * 64 + c] = v[e];
        }
        const f32x4* xp = (const f32x4*)(x + ((size_t)n * 64 + c) * 4096 + d * 256 + h * 16);
        for (int r = 0; r < 4; ++r) {
            f32x4 v = xp[r];
            for (int e = 0; e < 4; ++e) sX[(r * 4 + e) * 64 + c] = v[e];
        }
    }
    __syncthreads();

    int lane = t & 63;
    int wid  = t >> 6;          // wave id: q-range [wid*256, wid*256+256)
    int colq = lane & 15;
    int quad = lane >> 4;

    // ---- A fragments (b-operand): lane holds A[o = mt*16+colq][c = kt*32+quad*8+j] ----
    s16x8 afrag[4][2];
    for (int mt = 0; mt < 4; ++mt) {
        int o = mt * 16 + colq;
        for (int kt = 0; kt < 2; ++kt) {
            int c0 = kt * 32 + quad * 8;
            const float* ap = &sA[o * 68 + c0];
            f32x4 f0 = *(const f32x4*)ap;
            f32x4 f1 = *(const f32x4*)(ap + 4);
            s16x8 fr;
            fr[0] = (short)f2bf(f0[0]); fr[1] = (short)f2bf(f0[1]);
            fr[2] = (short)f2bf(f0[2]); fr[3] = (short)f2bf(f0[3]);
            fr[4] = (short)f2bf(f1[0]); fr[5] = (short)f2bf(f1[1]);
            fr[6] = (short)f2bf(f1[2]); fr[7] = (short)f2bf(f1[3]);
            afrag[mt][kt] = fr;
        }
    }
    // acc init = K[o]; with rows=q, cols=o: lane's column is o = mt*16+colq (all 4 regs same K)
    f32x4 kinit[4];
    for (int mt = 0; mt < 4; ++mt) {
        float kv = sK[mt * 16 + colq];
        kinit[mt][0] = kv; kinit[mt][1] = kv; kinit[mt][2] = kv; kinit[mt][3] = kv;
    }

    size_t base_n = (size_t)n << 24;   // n * 64 * 262144
    for (int nt = 0; nt < 16; ++nt) {
        int q0   = wid * 256 + nt * 16;
        int ij   = q0 >> 6;            // (i*4+j), fixed across the 16-wide tile
        int Wb   = q0 & 63;
        int Woff = Wb + colq;          // W = 4w+k, contiguous in memory
        int wi   = Woff >> 2;
        int kf   = Woff & 3;
        int ijk  = ij * 4 + kf;

        // B fragments (a-operand): lane holds B[c = kt*32+quad*8+j][q = q0+colq]
        s16x8 bfrag[2];
        for (int kt = 0; kt < 2; ++kt) {
            int c0 = kt * 32 + quad * 8;
            const float* wpp = &sW[ijk * 64 + c0];
            const float* xpp = &sX[wi  * 64 + c0];
            f32x4 w0 = *(const f32x4*)wpp, w1 = *(const f32x4*)(wpp + 4);
            f32x4 x0 = *(const f32x4*)xpp, x1 = *(const f32x4*)(xpp + 4);
            s16x8 fr;
            fr[0] = (short)f2bf(w0[0] * x0[0]); fr[1] = (short)f2bf(w0[1] * x0[1]);
            fr[2] = (short)f2bf(w0[2] * x0[2]); fr[3] = (short)f2bf(w0[3] * x0[3]);
            fr[4] = (short)f2bf(w1[0] * x1[0]); fr[5] = (short)f2bf(w1[1] * x1[1]);
            fr[6] = (short)f2bf(w1[2] * x1[2]); fr[7] = (short)f2bf(w1[3] * x1[3]);
            bfrag[kt] = fr;
        }

        int i_f = ij >> 2, j_f = ij & 3;
        // lane's 4 acc regs are rows q = q0 + quad*4 + {0..3} -> W = Wb + quad*4 + {0..3}
        size_t sp = (size_t)((4 * d + i_f) * 4096 + (4 * h + j_f) * 64 + Wb + quad * 4);
        for (int mt = 0; mt < 4; ++mt) {
            f32x4 acc = kinit[mt];
            acc = __builtin_amdgcn_mfma_f32_16x16x32_bf16(bfrag[0], afrag[mt][0], acc, 0, 0, 0);
            acc = __builtin_amdgcn_mfma_f32_16x16x32_bf16(bfrag[1], afrag[mt][1], acc, 0, 0, 0);
            int o = mt * 16 + colq;
            float* op = out + base_n + ((size_t)o << 18) + sp;
            *(f32x4*)op = acc;        // 16B store, 4 consecutive W of channel o
        }
    }
}

extern "C" void kernel_launch(void* const* d_in, const int* in_sizes, int n_in,
                              void* d_out, int out_size, void* d_ws, size_t ws_size,
                              hipStream_t stream) {
    const float* x     = (const float*)d_in[0];
    const float* w_ct  = (const float*)d_in[1];
    const float* b_ct  = (const float*)d_in[2];
    const float* gamma = (const float*)d_in[3];
    const float* beta  = (const float*)d_in[4];
    const float* w_pw  = (const float*)d_in[5];
    float* ws  = (float*)d_ws;
    float* out = (float*)d_out;

    k_reduce<<<128, 256, 0, stream>>>(x, ws);
    k_stats<<<1, 256, 0, stream>>>(w_ct, b_ct, gamma, beta, w_pw, ws);
    k_main<<<512, 256, 0, stream>>>(x, w_ct, ws, out);
}

// Round 3
// 170.271 us; speedup vs baseline: 1.0104x; 1.0104x over previous
//
#include <hip/hip_runtime.h>

typedef unsigned short u16;
typedef __attribute__((ext_vector_type(8))) short s16x8;
typedef __attribute__((ext_vector_type(4))) float f32x4;
typedef __attribute__((ext_vector_type(4))) unsigned int u32x4;

// f32 -> bf16 bits, round-to-nearest-even (finite values)
__device__ __forceinline__ u16 f2bf(float f) {
    unsigned u = __builtin_bit_cast(unsigned, f);
    u += 0x7fffu + ((u >> 16) & 1u);
    return (u16)(u >> 16);
}
__device__ __forceinline__ float lo_bf(unsigned v) {
    return __builtin_bit_cast(float, v << 16);
}
__device__ __forceinline__ float hi_bf(unsigned v) {
    return __builtin_bit_cast(float, v & 0xffff0000u);
}

// ws layout (floats): [0..127] Sx[n][c], [128..255] Sx2[n][c]
#define WS_SX   0
#define WS_SX2  128

// ---------------- Kernel 1: per-(n,c) moments of x (fp32) ----------------
__global__ __launch_bounds__(256) void k_reduce(const float* __restrict__ x,
                                                float* __restrict__ ws) {
    int nc = blockIdx.x;                       // 0..127, one 4096-elem channel each
    const f32x4* p = (const f32x4*)(x + (size_t)nc * 4096);
    int t = threadIdx.x;
    float s = 0.f, s2 = 0.f;
    for (int it = 0; it < 4; ++it) {
        f32x4 v = p[t + it * 256];
        for (int e = 0; e < 4; ++e) { s += v[e]; s2 += v[e] * v[e]; }
    }
    for (int off = 32; off; off >>= 1) {
        s  += __shfl_down(s, off);
        s2 += __shfl_down(s2, off);
    }
    __shared__ float rs[4], rs2[4];
    int lane = t & 63, wv = t >> 6;
    if (lane == 0) { rs[wv] = s; rs2[wv] = s2; }
    __syncthreads();
    if (t == 0) {
        ws[WS_SX  + nc] = rs[0] + rs[1] + rs[2] + rs[3];
        ws[WS_SX2 + nc] = rs2[0] + rs2[1] + rs2[2] + rs2[3];
    }
}

// ---------------- Kernel 2: fused stats + upsample + GN + pointwise --------
// Block = (n, d, h), 512 blocks. out[n,o,4d+i,4h+j,W] for all o,i,j,W.
// GEMM (transposed): D[q][o] = B^T[q][c] @ A^T[c][o] + K[o]
//   q = (i*4+j)*64 + W, W = 4w+k,  B[c][q] = w_ct[c,ijk] * x[n,c,d,h,w]
// mfma(bfrag, afrag, acc): acc rows = q (4 consecutive W -> float4 NT store).
#define SWS 96   // sW/sX row stride in shorts (192 B: 2-way bank alias = free)
__global__ __launch_bounds__(256) void k_main(const float* __restrict__ x,
                                              const float* __restrict__ w_ct,
                                              const float* __restrict__ b_ct,
                                              const float* __restrict__ gamma,
                                              const float* __restrict__ beta,
                                              const float* __restrict__ w_pw,
                                              const float* __restrict__ ws,
                                              float* __restrict__ out) {
    __shared__ __align__(16) u16   sWb[64 * SWS];   // [ijk][c] bf16
    __shared__ __align__(16) u16   sXb[16 * SWS];   // [w][c]   bf16
    __shared__ __align__(16) float sA[64 * 68];     // [o][c] fp32, stride 68
    __shared__ float sK[64];
    __shared__ float p_sw[256], p_sw2[256];         // partial w-moments [qr][c]
    __shared__ float s_b[64], s_g[64], s_be[64];
    __shared__ float s_mi[2];                       // mean, inv_std

    int t = threadIdx.x;
    int b = blockIdx.x;
    int n = b >> 8, d = (b >> 4) & 15, h = b & 15;

    // ---- stage w_ct (transpose + bf16 + partial moments), x row, small vecs ----
    {
        int c = t & 63, qr = t >> 6;               // 4 threads per channel
        const f32x4* wp = (const f32x4*)(w_ct + c * 64 + qr * 16);
        float sw = 0.f, sw2 = 0.f;
        for (int r = 0; r < 4; ++r) {
            f32x4 v = wp[r];
            for (int e = 0; e < 4; ++e) {
                float f = v[e];
                sw += f; sw2 += f * f;
                sWb[(qr * 16 + r * 4 + e) * SWS + c] = f2bf(f);
            }
        }
        p_sw[t] = sw; p_sw2[t] = sw2;
    }
    if (t < 64) {
        int c = t;
        const f32x4* xp = (const f32x4*)(x + ((size_t)n * 64 + c) * 4096 + d * 256 + h * 16);
        for (int r = 0; r < 4; ++r) {
            f32x4 v = xp[r];
            for (int e = 0; e < 4; ++e) sXb[(r * 4 + e) * SWS + c] = f2bf(v[e]);
        }
        s_b[c] = b_ct[c]; s_g[c] = gamma[c]; s_be[c] = beta[c];
    }
    __syncthreads();

    // ---- analytic GroupNorm stats (wave 0) ----
    if (t < 64) {
        int c = t;
        float sw  = p_sw[c]  + p_sw[64 + c]  + p_sw[128 + c]  + p_sw[192 + c];
        float sw2 = p_sw2[c] + p_sw2[64 + c] + p_sw2[128 + c] + p_sw2[192 + c];
        float sx  = ws[WS_SX  + n * 64 + c];
        float sx2 = ws[WS_SX2 + n * 64 + c];
        float bc  = s_b[c];
        float ty  = sw  * sx  + 262144.f * bc;
        float ty2 = sw2 * sx2 + 2.f * bc * sw * sx + 262144.f * bc * bc;
        for (int off = 32; off; off >>= 1) {
            ty  += __shfl_down(ty, off);
            ty2 += __shfl_down(ty2, off);
        }
        if (t == 0) {
            float mean = ty * (1.f / 16777216.f);
            float var  = ty2 * (1.f / 16777216.f) - mean * mean;
            s_mi[0] = mean;
            s_mi[1] = rsqrtf(var + 1e-5f);
        }
    }
    __syncthreads();

    float mean = s_mi[0], inv = s_mi[1];
    // ---- A[o][c] = w_pw[o,c] * gamma[c] * inv  (all threads, 16 each) ----
    for (int k = 0; k < 16; ++k) {
        int idx = t + k * 256;
        int c = idx & 63;
        sA[(idx >> 6) * 68 + c] = w_pw[idx] * s_g[c] * inv;
    }
    // ---- K[o] = sum_c w_pw[o,c] * (g[c]*inv*(b[c]-mean) + beta[c]) ----
    if (t < 64) {
        int o = t;
        const f32x4* wp = (const f32x4*)(w_pw + o * 64);
        float k = 0.f;
        for (int r = 0; r < 16; ++r) {
            f32x4 v = wp[r];
            for (int e = 0; e < 4; ++e) {
                int c = r * 4 + e;
                k += v[e] * (s_g[c] * inv * (s_b[c] - mean) + s_be[c]);
            }
        }
        sK[o] = k;
    }
    __syncthreads();

    int lane = t & 63;
    int wid  = t >> 6;          // wave id: q-range [wid*256, wid*256+256)
    int colq = lane & 15;
    int quad = lane >> 4;

    // ---- A fragments (b-operand): lane holds A[o=mt*16+colq][c=kt*32+quad*8+j] ----
    s16x8 afrag[4][2];
    for (int mt = 0; mt < 4; ++mt) {
        int o = mt * 16 + colq;
        for (int kt = 0; kt < 2; ++kt) {
            int c0 = kt * 32 + quad * 8;
            const float* ap = &sA[o * 68 + c0];
            f32x4 f0 = *(const f32x4*)ap;
            f32x4 f1 = *(const f32x4*)(ap + 4);
            s16x8 fr;
            fr[0] = (short)f2bf(f0[0]); fr[1] = (short)f2bf(f0[1]);
            fr[2] = (short)f2bf(f0[2]); fr[3] = (short)f2bf(f0[3]);
            fr[4] = (short)f2bf(f1[0]); fr[5] = (short)f2bf(f1[1]);
            fr[6] = (short)f2bf(f1[2]); fr[7] = (short)f2bf(f1[3]);
            afrag[mt][kt] = fr;
        }
    }
    // acc init: lane's column is o = mt*16+colq, all 4 row-regs share K[o]
    f32x4 kinit[4];
    for (int mt = 0; mt < 4; ++mt) {
        float kv = sK[mt * 16 + colq];
        kinit[mt][0] = kv; kinit[mt][1] = kv; kinit[mt][2] = kv; kinit[mt][3] = kv;
    }

    size_t base_n = (size_t)n << 24;   // n * 64 * 262144
    for (int nt = 0; nt < 16; ++nt) {
        int q0   = wid * 256 + nt * 16;
        int ij   = q0 >> 6;            // i*4+j (fixed across the 16-wide tile)
        int Wb   = q0 & 63;            // multiple of 16
        int Woff = Wb + colq;
        int wi   = Woff >> 2;
        int kf   = Woff & 3;
        int ijk  = ij * 4 + kf;

        // B fragments (a-operand): lane holds B[c=kt*32+quad*8+j][q=q0+colq]
        s16x8 bfrag[2];
        for (int kt = 0; kt < 2; ++kt) {
            int c0 = kt * 32 + quad * 8;
            u32x4 wv = *(const u32x4*)&sWb[ijk * SWS + c0];
            u32x4 xv = *(const u32x4*)&sXb[wi  * SWS + c0];
            s16x8 fr;
            for (int e = 0; e < 4; ++e) {
                float pl = lo_bf(wv[e]) * lo_bf(xv[e]);
                float ph = hi_bf(wv[e]) * hi_bf(xv[e]);
                fr[2 * e]     = (short)f2bf(pl);
                fr[2 * e + 1] = (short)f2bf(ph);
            }
            bfrag[kt] = fr;
        }

        int i_f = ij >> 2, j_f = ij & 3;
        // lane's 4 acc rows are q = q0 + quad*4 + {0..3} -> W = Wb + quad*4 + {0..3}
        size_t sp = (size_t)((4 * d + i_f) * 4096 + (4 * h + j_f) * 64 + Wb + quad * 4);
        for (int mt = 0; mt < 4; ++mt) {
            f32x4 acc = kinit[mt];
            acc = __builtin_amdgcn_mfma_f32_16x16x32_bf16(bfrag[0], afrag[mt][0], acc, 0, 0, 0);
            acc = __builtin_amdgcn_mfma_f32_16x16x32_bf16(bfrag[1], afrag[mt][1], acc, 0, 0, 0);
            int o = mt * 16 + colq;
            float* op = out + base_n + ((size_t)o << 18) + sp;
            __builtin_nontemporal_store(acc, (f32x4*)op);  // 16B streaming store
        }
    }
}

extern "C" void kernel_launch(void* const* d_in, const int* in_sizes, int n_in,
                              void* d_out, int out_size, void* d_ws, size_t ws_size,
                              hipStream_t stream) {
    const float* x     = (const float*)d_in[0];
    const float* w_ct  = (const float*)d_in[1];
    const float* b_ct  = (const float*)d_in[2];
    const float* gamma = (const float*)d_in[3];
    const float* beta  = (const float*)d_in[4];
    const float* w_pw  = (const float*)d_in[5];
    float* ws  = (float*)d_ws;
    float* out = (float*)d_out;

    k_reduce<<<128, 256, 0, stream>>>(x, ws);
    k_main<<<512, 256, 0, stream>>>(x, w_ct, b_ct, gamma, beta, w_pw, ws, out);
}